// Round 7
// baseline (729.939 us; speedup 1.0000x reference)
//
#include <hip/hip_runtime.h>
#include <stdint.h>

#define TB 256

// ---------------- utility ----------------
__global__ void zero_u32(uint32_t* __restrict__ p, int n) {
    int i = blockIdx.x * blockDim.x + threadIdx.x;
    if (i < n) p[i] = 0u;
}

// ---------------- degree histogram ----------------
__global__ void hist_kernel(const int* __restrict__ dst, int E, int* __restrict__ cnt) {
    int e = blockIdx.x * blockDim.x + threadIdx.x;
    if (e < E) atomicAdd(&cnt[dst[e]], 1);
}

__global__ void dinv_kernel(const int* __restrict__ cnt, float* __restrict__ dinv, int N) {
    int n = blockIdx.x * blockDim.x + threadIdx.x;
    if (n < N) dinv[n] = rsqrtf((float)cnt[n] + 1.0f);   // +1 for self-loop
}

// ---------------- exclusive scan over cnt -> row_ptr (3 phases) ----------------
// phase 1: per-1024-chunk exclusive scan, block sums out
__global__ __launch_bounds__(256) void scan1_kernel(const int* __restrict__ cnt, int N,
                                                    int* __restrict__ rp, int* __restrict__ bsum) {
    __shared__ int sh[256];
    int t = threadIdx.x;
    int base = blockIdx.x * 1024 + t * 4;
    int v0 = (base + 0 < N) ? cnt[base + 0] : 0;
    int v1 = (base + 1 < N) ? cnt[base + 1] : 0;
    int v2 = (base + 2 < N) ? cnt[base + 2] : 0;
    int v3 = (base + 3 < N) ? cnt[base + 3] : 0;
    int s = v0 + v1 + v2 + v3;
    sh[t] = s;
    __syncthreads();
    for (int off = 1; off < 256; off <<= 1) {
        int add = (t >= off) ? sh[t - off] : 0;
        __syncthreads();
        sh[t] += add;
        __syncthreads();
    }
    int incl = sh[t];
    if (t == 255) bsum[blockIdx.x] = incl;
    int run = incl - s;  // exclusive
    if (base + 0 < N) rp[base + 0] = run; run += v0;
    if (base + 1 < N) rp[base + 1] = run; run += v1;
    if (base + 2 < N) rp[base + 2] = run; run += v2;
    if (base + 3 < N) rp[base + 3] = run;
}

// phase 2: single-block exclusive scan of block sums (nblk <= 256)
__global__ __launch_bounds__(256) void scan2_kernel(int* __restrict__ bsum, int nblk) {
    __shared__ int sh[256];
    int t = threadIdx.x;
    int v = (t < nblk) ? bsum[t] : 0;
    sh[t] = v;
    __syncthreads();
    for (int off = 1; off < 256; off <<= 1) {
        int add = (t >= off) ? sh[t - off] : 0;
        __syncthreads();
        sh[t] += add;
        __syncthreads();
    }
    if (t < nblk) bsum[t] = sh[t] - v;  // exclusive
}

// phase 3: add block offsets, copy to fill counters, set rp[N]=E
__global__ void scan3_kernel(int* __restrict__ rp, int* __restrict__ rfill,
                             const int* __restrict__ bsum, int N, int E) {
    int i = blockIdx.x * blockDim.x + threadIdx.x;
    if (i < N) {
        int v = rp[i] + bsum[i >> 10];
        rp[i] = v;
        rfill[i] = v;
    }
    if (i == 0) rp[N] = E;
}

// ---------------- CSR fill: sorted (src, weight) per dst ----------------
__global__ void fill_kernel(const int* __restrict__ src, const int* __restrict__ dst, int E,
                            int* __restrict__ rfill, int2* __restrict__ edges,
                            const float* __restrict__ dinv) {
    int e = blockIdx.x * blockDim.x + threadIdx.x;
    if (e < E) {
        int s = src[e], d = dst[e];
        int pos = atomicAdd(&rfill[d], 1);
        int2 pr;
        pr.x = s;
        pr.y = __float_as_int(dinv[s] * dinv[d]);
        edges[pos] = pr;
    }
}

// ---------------- GEMM: Y[N,128] = X[N,128] @ W[128,128] ----------------
// W staged in LDS (64KB); 32 nodes x 128 feats per tile; thread = 4 nodes x 4 feats.
__global__ __launch_bounds__(256) void gemm128_kernel(const float* __restrict__ X,
                                                      const float* __restrict__ W,
                                                      float* __restrict__ Y,
                                                      int N, int ntiles) {
    __shared__ float Ws[128 * 128];
    for (int i = threadIdx.x; i < 128 * 128 / 4; i += 256)
        ((float4*)Ws)[i] = ((const float4*)W)[i];
    __syncthreads();

    int tf = threadIdx.x & 31;   // feature group (f0 = tf*4)
    int tn = threadIdx.x >> 5;   // node group   (j0 = tn*4)
    int f0 = tf * 4;
    int j0 = tn * 4;

    for (int tile = blockIdx.x; tile < ntiles; tile += gridDim.x) {
        int n0 = tile * 32;
        int nn0 = min(n0 + j0 + 0, N - 1);
        int nn1 = min(n0 + j0 + 1, N - 1);
        int nn2 = min(n0 + j0 + 2, N - 1);
        int nn3 = min(n0 + j0 + 3, N - 1);
        const float* xr0 = X + (size_t)nn0 * 128;
        const float* xr1 = X + (size_t)nn1 * 128;
        const float* xr2 = X + (size_t)nn2 * 128;
        const float* xr3 = X + (size_t)nn3 * 128;
        float4 a0 = {0, 0, 0, 0}, a1 = {0, 0, 0, 0}, a2 = {0, 0, 0, 0}, a3 = {0, 0, 0, 0};
#pragma unroll 8
        for (int k = 0; k < 128; ++k) {
            float4 wv = *(const float4*)(Ws + k * 128 + f0);
            float x0 = xr0[k], x1 = xr1[k], x2 = xr2[k], x3 = xr3[k];
            a0.x = fmaf(x0, wv.x, a0.x); a0.y = fmaf(x0, wv.y, a0.y);
            a0.z = fmaf(x0, wv.z, a0.z); a0.w = fmaf(x0, wv.w, a0.w);
            a1.x = fmaf(x1, wv.x, a1.x); a1.y = fmaf(x1, wv.y, a1.y);
            a1.z = fmaf(x1, wv.z, a1.z); a1.w = fmaf(x1, wv.w, a1.w);
            a2.x = fmaf(x2, wv.x, a2.x); a2.y = fmaf(x2, wv.y, a2.y);
            a2.z = fmaf(x2, wv.z, a2.z); a2.w = fmaf(x2, wv.w, a2.w);
            a3.x = fmaf(x3, wv.x, a3.x); a3.y = fmaf(x3, wv.y, a3.y);
            a3.z = fmaf(x3, wv.z, a3.z); a3.w = fmaf(x3, wv.w, a3.w);
        }
        int n;
        n = n0 + j0 + 0; if (n < N) *(float4*)(Y + (size_t)n * 128 + f0) = a0;
        n = n0 + j0 + 1; if (n < N) *(float4*)(Y + (size_t)n * 128 + f0) = a1;
        n = n0 + j0 + 2; if (n < N) *(float4*)(Y + (size_t)n * 128 + f0) = a2;
        n = n0 + j0 + 3; if (n < N) *(float4*)(Y + (size_t)n * 128 + f0) = a3;
    }
}

// ---------------- conv scatter (CSR, one wave per node) + bias + relu ----------------
__global__ __launch_bounds__(256) void conv_kernel(const float* __restrict__ T,
                                                   const int* __restrict__ rp,
                                                   const int2* __restrict__ edges,
                                                   const float* __restrict__ dinv,
                                                   const float* __restrict__ bias,
                                                   float* __restrict__ OUT, int N) {
    int wid = (blockIdx.x * TB + threadIdx.x) >> 6;  // one wave per node
    int lane = threadIdx.x & 63;
    if (wid >= N) return;
    int d = wid;
    float dv = dinv[d];
    float2 td = *(const float2*)(T + (size_t)d * 128 + lane * 2);
    float2 acc;
    acc.x = dv * dv * td.x;
    acc.y = dv * dv * td.y;
    int e0 = rp[d], e1 = rp[d + 1];
#pragma unroll 4
    for (int e = e0; e < e1; ++e) {
        int2 pr = edges[e];
        float w = __int_as_float(pr.y);
        float2 tv = *(const float2*)(T + (size_t)pr.x * 128 + lane * 2);
        acc.x = fmaf(w, tv.x, acc.x);
        acc.y = fmaf(w, tv.y, acc.y);
    }
    float2 b = *(const float2*)(bias + lane * 2);
    float2 o;
    o.x = fmaxf(acc.x + b.x, 0.0f);
    o.y = fmaxf(acc.y + b.y, 0.0f);
    *(float2*)(OUT + (size_t)d * 128 + lane * 2) = o;
}

// ---------------- mean pool (batch sorted: accumulate, flush on boundary) ----------------
#define NPB 256
__global__ __launch_bounds__(128) void pool_kernel(const float* __restrict__ Hh,
                                                   const int* __restrict__ batch, int N,
                                                   float* __restrict__ gsum, int* __restrict__ gcnt) {
    int f = threadIdx.x;  // 0..127
    int n0 = blockIdx.x * NPB;
    if (n0 >= N) return;
    int n1 = min(n0 + NPB, N);
    int cur = batch[n0];
    float acc = 0.0f;
    int c = 0;
    for (int n = n0; n < n1; ++n) {
        int b = batch[n];
        if (b != cur) {
            atomicAdd(&gsum[cur * 128 + f], acc);
            if (f == 0) atomicAdd(&gcnt[cur], c);
            acc = 0.0f; c = 0; cur = b;
        }
        acc += Hh[(size_t)n * 128 + f];
        c++;
    }
    atomicAdd(&gsum[cur * 128 + f], acc);
    if (f == 0) atomicAdd(&gcnt[cur], c);
}

// ---------------- head: mean, fc1+relu, fc2, log_softmax ----------------
__global__ __launch_bounds__(128) void head_kernel(const float* __restrict__ gsum,
                                                   const int* __restrict__ gcnt,
                                                   const float* __restrict__ fcW1,
                                                   const float* __restrict__ fcb1,
                                                   const float* __restrict__ fcW2,
                                                   const float* __restrict__ fcb2,
                                                   float* __restrict__ out) {
    __shared__ float gx[128], hid[128], lg[10];
    int g = blockIdx.x, t = threadIdx.x;
    float cntf = fmaxf((float)gcnt[g], 1.0f);
    gx[t] = gsum[g * 128 + t] / cntf;
    __syncthreads();
    float a = fcb1[t];
    for (int k = 0; k < 128; ++k) a = fmaf(gx[k], fcW1[k * 128 + t], a);
    hid[t] = fmaxf(a, 0.0f);
    __syncthreads();
    if (t < 10) {
        float a2 = fcb2[t];
        for (int k = 0; k < 128; ++k) a2 = fmaf(hid[k], fcW2[k * 10 + t], a2);
        lg[t] = a2;
    }
    __syncthreads();
    if (t < 10) {
        float m = -1e30f;
        for (int j = 0; j < 10; ++j) m = fmaxf(m, lg[j]);
        float se = 0.0f;
        for (int j = 0; j < 10; ++j) se += expf(lg[j] - m);
        out[g * 10 + t] = lg[t] - m - logf(se);
    }
}

// ---------------- launch ----------------
extern "C" void kernel_launch(void* const* d_in, const int* in_sizes, int n_in,
                              void* d_out, int out_size, void* d_ws, size_t ws_size,
                              hipStream_t stream) {
    const float* x    = (const float*)d_in[0];
    const int*   ei   = (const int*)d_in[1];
    const int*   batch= (const int*)d_in[2];
    const float* W1   = (const float*)d_in[3];
    const float* b1   = (const float*)d_in[4];
    const float* W2   = (const float*)d_in[5];
    const float* b2   = (const float*)d_in[6];
    const float* fcW1 = (const float*)d_in[7];
    const float* fcb1 = (const float*)d_in[8];
    const float* fcW2 = (const float*)d_in[9];
    const float* fcb2 = (const float*)d_in[10];
    float* out = (float*)d_out;

    int N = in_sizes[0] / 128;
    int E = in_sizes[1] / 2;
    const int* src = ei;
    const int* dst = ei + E;

    // workspace carve-out (256B aligned)
    char* basep = (char*)d_ws;
    size_t off = 0;
    auto alloc = [&](size_t bytes) -> void* {
        off = (off + 255) & ~(size_t)255;
        void* p = basep + off;
        off += bytes;
        return p;
    };
    float* dinv  = (float*)alloc((size_t)N * 4);
    int*   cnt   = (int*)alloc((size_t)N * 4);
    int*   rp    = (int*)alloc((size_t)(N + 1) * 4);
    int*   rfill = (int*)alloc((size_t)N * 4);
    int*   bsum  = (int*)alloc(1024 * 4);
    int2*  edges = (int2*)alloc((size_t)E * 8);
    float* A     = (float*)alloc((size_t)N * 128 * 4);
    float* B     = (float*)alloc((size_t)N * 128 * 4);
    float* gsum  = (float*)alloc(64 * 128 * 4);
    int*   gcnt  = (int*)alloc(64 * 4);

    int nblk = (N + 1023) / 1024;
    int ntiles = (N + 31) / 32;

    // 1) degrees + dinv
    zero_u32<<<(N + TB - 1) / TB, TB, 0, stream>>>((uint32_t*)cnt, N);
    hist_kernel<<<(E + TB - 1) / TB, TB, 0, stream>>>(dst, E, cnt);
    dinv_kernel<<<(N + TB - 1) / TB, TB, 0, stream>>>(cnt, dinv, N);

    // 2) CSR build (counting sort by dst)
    scan1_kernel<<<nblk, 256, 0, stream>>>(cnt, N, rp, bsum);
    scan2_kernel<<<1, 256, 0, stream>>>(bsum, nblk);
    scan3_kernel<<<(N + TB - 1) / TB, TB, 0, stream>>>(rp, rfill, bsum, N, E);
    fill_kernel<<<(E + TB - 1) / TB, TB, 0, stream>>>(src, dst, E, rfill, edges, dinv);

    // 3) conv1: A = x@W1 ; B = relu(scatter(A) + b1)
    gemm128_kernel<<<1024, 256, 0, stream>>>(x, W1, A, N, ntiles);
    conv_kernel<<<(N + 3) / 4, TB, 0, stream>>>(A, rp, edges, dinv, b1, B, N);

    // 4) conv2: A = B@W2 ; B = relu(scatter(A) + b2)
    gemm128_kernel<<<1024, 256, 0, stream>>>(B, W2, A, N, ntiles);
    conv_kernel<<<(N + 3) / 4, TB, 0, stream>>>(A, rp, edges, dinv, b2, B, N);

    // 5) mean pool
    zero_u32<<<(64 * 128 + TB - 1) / TB, TB, 0, stream>>>((uint32_t*)gsum, 64 * 128);
    zero_u32<<<1, 64, 0, stream>>>((uint32_t*)gcnt, 64);
    pool_kernel<<<(N + NPB - 1) / NPB, 128, 0, stream>>>(B, batch, N, gsum, gcnt);

    // 6) head
    head_kernel<<<64, 128, 0, stream>>>(gsum, gcnt, fcW1, fcb1, fcW2, fcb2, out);
}

// Round 8
// 628.117 us; speedup vs baseline: 1.1621x; 1.1621x over previous
//
#include <hip/hip_runtime.h>
#include <stdint.h>

#define TB 256

// ---------------- bf16 helpers (bit-level, RTNE) ----------------
__device__ __forceinline__ float blo(uint32_t v) { return __uint_as_float(v << 16); }
__device__ __forceinline__ float bhi(uint32_t v) { return __uint_as_float(v & 0xffff0000u); }
__device__ __forceinline__ uint32_t f2b(float f) {  // RTNE, returns low 16 bits
    uint32_t u = __float_as_uint(f);
    return (u + 0x7fffu + ((u >> 16) & 1u)) >> 16;
}
__device__ __forceinline__ uint32_t pack2(float lo, float hi) {
    return f2b(lo) | (f2b(hi) << 16);
}

// ---------------- utility ----------------
__global__ void zero_u32(uint32_t* __restrict__ p, int n) {
    int i = blockIdx.x * blockDim.x + threadIdx.x;
    if (i < n) p[i] = 0u;
}

// ---------------- degree histogram ----------------
__global__ void hist_kernel(const int* __restrict__ dst, int E, int* __restrict__ cnt) {
    int e = blockIdx.x * blockDim.x + threadIdx.x;
    if (e < E) atomicAdd(&cnt[dst[e]], 1);
}

__global__ void dinv_kernel(const int* __restrict__ cnt, float* __restrict__ dinv, int N) {
    int n = blockIdx.x * blockDim.x + threadIdx.x;
    if (n < N) dinv[n] = rsqrtf((float)cnt[n] + 1.0f);   // +1 for self-loop
}

// ---------------- exclusive scan over cnt -> row_ptr (3 phases) ----------------
__global__ __launch_bounds__(256) void scan1_kernel(const int* __restrict__ cnt, int N,
                                                    int* __restrict__ rp, int* __restrict__ bsum) {
    __shared__ int sh[256];
    int t = threadIdx.x;
    int base = blockIdx.x * 1024 + t * 4;
    int v0 = (base + 0 < N) ? cnt[base + 0] : 0;
    int v1 = (base + 1 < N) ? cnt[base + 1] : 0;
    int v2 = (base + 2 < N) ? cnt[base + 2] : 0;
    int v3 = (base + 3 < N) ? cnt[base + 3] : 0;
    int s = v0 + v1 + v2 + v3;
    sh[t] = s;
    __syncthreads();
    for (int off = 1; off < 256; off <<= 1) {
        int add = (t >= off) ? sh[t - off] : 0;
        __syncthreads();
        sh[t] += add;
        __syncthreads();
    }
    int incl = sh[t];
    if (t == 255) bsum[blockIdx.x] = incl;
    int run = incl - s;  // exclusive
    if (base + 0 < N) rp[base + 0] = run; run += v0;
    if (base + 1 < N) rp[base + 1] = run; run += v1;
    if (base + 2 < N) rp[base + 2] = run; run += v2;
    if (base + 3 < N) rp[base + 3] = run;
}

__global__ __launch_bounds__(256) void scan2_kernel(int* __restrict__ bsum, int nblk) {
    __shared__ int sh[256];
    int t = threadIdx.x;
    int v = (t < nblk) ? bsum[t] : 0;
    sh[t] = v;
    __syncthreads();
    for (int off = 1; off < 256; off <<= 1) {
        int add = (t >= off) ? sh[t - off] : 0;
        __syncthreads();
        sh[t] += add;
        __syncthreads();
    }
    if (t < nblk) bsum[t] = sh[t] - v;  // exclusive
}

__global__ void scan3_kernel(int* __restrict__ rp, int* __restrict__ rfill,
                             const int* __restrict__ bsum, int N, int E) {
    int i = blockIdx.x * blockDim.x + threadIdx.x;
    if (i < N) {
        int v = rp[i] + bsum[i >> 10];
        rp[i] = v;
        rfill[i] = v;
    }
    if (i == 0) rp[N] = E;
}

// ---------------- CSR fill: (src, weight) per dst ----------------
__global__ void fill_kernel(const int* __restrict__ src, const int* __restrict__ dst, int E,
                            int* __restrict__ rfill, int2* __restrict__ edges,
                            const float* __restrict__ dinv) {
    int e = blockIdx.x * blockDim.x + threadIdx.x;
    if (e < E) {
        int s = src[e], d = dst[e];
        int pos = atomicAdd(&rfill[d], 1);
        int2 pr;
        pr.x = s;
        pr.y = __float_as_int(dinv[s] * dinv[d]);
        edges[pos] = pr;
    }
}

// ---------------- GEMM: Y[N,128](bf16) = X[N,128] @ W[128,128](f32) ----------------
// W staged in LDS (64KB); 32 nodes x 128 feats per tile; thread = 4 nodes x 4 feats.
// BF16IN: X rows are bf16 (packed 2/uint); else fp32. Accumulate fp32, emit bf16.
template <bool BF16IN>
__global__ __launch_bounds__(256) void gemm128_kernel(const void* __restrict__ Xv,
                                                      const float* __restrict__ W,
                                                      uint32_t* __restrict__ Y,  // [N*64] bf16x2
                                                      int N, int ntiles) {
    __shared__ float Ws[128 * 128];
    for (int i = threadIdx.x; i < 128 * 128 / 4; i += 256)
        ((float4*)Ws)[i] = ((const float4*)W)[i];
    __syncthreads();

    int tf = threadIdx.x & 31;   // feature group (f0 = tf*4)
    int tn = threadIdx.x >> 5;   // node group   (j0 = tn*4)
    int f0 = tf * 4;
    int j0 = tn * 4;

    for (int tile = blockIdx.x; tile < ntiles; tile += gridDim.x) {
        int n0 = tile * 32;
        int nn0 = min(n0 + j0 + 0, N - 1);
        int nn1 = min(n0 + j0 + 1, N - 1);
        int nn2 = min(n0 + j0 + 2, N - 1);
        int nn3 = min(n0 + j0 + 3, N - 1);
        float4 a0 = {0, 0, 0, 0}, a1 = {0, 0, 0, 0}, a2 = {0, 0, 0, 0}, a3 = {0, 0, 0, 0};

        if (BF16IN) {
            const uint16_t* xr0 = (const uint16_t*)Xv + (size_t)nn0 * 128;
            const uint16_t* xr1 = (const uint16_t*)Xv + (size_t)nn1 * 128;
            const uint16_t* xr2 = (const uint16_t*)Xv + (size_t)nn2 * 128;
            const uint16_t* xr3 = (const uint16_t*)Xv + (size_t)nn3 * 128;
#pragma unroll 4
            for (int k = 0; k < 128; k += 2) {
                float4 w0 = *(const float4*)(Ws + k * 128 + f0);
                float4 w1 = *(const float4*)(Ws + (k + 1) * 128 + f0);
                uint32_t u0 = *(const uint32_t*)(xr0 + k);
                uint32_t u1 = *(const uint32_t*)(xr1 + k);
                uint32_t u2 = *(const uint32_t*)(xr2 + k);
                uint32_t u3 = *(const uint32_t*)(xr3 + k);
                float x;
                x = blo(u0);
                a0.x = fmaf(x, w0.x, a0.x); a0.y = fmaf(x, w0.y, a0.y);
                a0.z = fmaf(x, w0.z, a0.z); a0.w = fmaf(x, w0.w, a0.w);
                x = bhi(u0);
                a0.x = fmaf(x, w1.x, a0.x); a0.y = fmaf(x, w1.y, a0.y);
                a0.z = fmaf(x, w1.z, a0.z); a0.w = fmaf(x, w1.w, a0.w);
                x = blo(u1);
                a1.x = fmaf(x, w0.x, a1.x); a1.y = fmaf(x, w0.y, a1.y);
                a1.z = fmaf(x, w0.z, a1.z); a1.w = fmaf(x, w0.w, a1.w);
                x = bhi(u1);
                a1.x = fmaf(x, w1.x, a1.x); a1.y = fmaf(x, w1.y, a1.y);
                a1.z = fmaf(x, w1.z, a1.z); a1.w = fmaf(x, w1.w, a1.w);
                x = blo(u2);
                a2.x = fmaf(x, w0.x, a2.x); a2.y = fmaf(x, w0.y, a2.y);
                a2.z = fmaf(x, w0.z, a2.z); a2.w = fmaf(x, w0.w, a2.w);
                x = bhi(u2);
                a2.x = fmaf(x, w1.x, a2.x); a2.y = fmaf(x, w1.y, a2.y);
                a2.z = fmaf(x, w1.z, a2.z); a2.w = fmaf(x, w1.w, a2.w);
                x = blo(u3);
                a3.x = fmaf(x, w0.x, a3.x); a3.y = fmaf(x, w0.y, a3.y);
                a3.z = fmaf(x, w0.z, a3.z); a3.w = fmaf(x, w0.w, a3.w);
                x = bhi(u3);
                a3.x = fmaf(x, w1.x, a3.x); a3.y = fmaf(x, w1.y, a3.y);
                a3.z = fmaf(x, w1.z, a3.z); a3.w = fmaf(x, w1.w, a3.w);
            }
        } else {
            const float* xr0 = (const float*)Xv + (size_t)nn0 * 128;
            const float* xr1 = (const float*)Xv + (size_t)nn1 * 128;
            const float* xr2 = (const float*)Xv + (size_t)nn2 * 128;
            const float* xr3 = (const float*)Xv + (size_t)nn3 * 128;
#pragma unroll 8
            for (int k = 0; k < 128; ++k) {
                float4 wv = *(const float4*)(Ws + k * 128 + f0);
                float x0 = xr0[k], x1 = xr1[k], x2 = xr2[k], x3 = xr3[k];
                a0.x = fmaf(x0, wv.x, a0.x); a0.y = fmaf(x0, wv.y, a0.y);
                a0.z = fmaf(x0, wv.z, a0.z); a0.w = fmaf(x0, wv.w, a0.w);
                a1.x = fmaf(x1, wv.x, a1.x); a1.y = fmaf(x1, wv.y, a1.y);
                a1.z = fmaf(x1, wv.z, a1.z); a1.w = fmaf(x1, wv.w, a1.w);
                a2.x = fmaf(x2, wv.x, a2.x); a2.y = fmaf(x2, wv.y, a2.y);
                a2.z = fmaf(x2, wv.z, a2.z); a2.w = fmaf(x2, wv.w, a2.w);
                a3.x = fmaf(x3, wv.x, a3.x); a3.y = fmaf(x3, wv.y, a3.y);
                a3.z = fmaf(x3, wv.z, a3.z); a3.w = fmaf(x3, wv.w, a3.w);
            }
        }
        // store bf16x2: feats f0..f0+3 -> uint idx n*64 + tf*2 + {0,1}
        int n;
        n = n0 + j0 + 0;
        if (n < N) { uint2 o = {pack2(a0.x, a0.y), pack2(a0.z, a0.w)};
                     *(uint2*)(Y + (size_t)n * 64 + tf * 2) = o; }
        n = n0 + j0 + 1;
        if (n < N) { uint2 o = {pack2(a1.x, a1.y), pack2(a1.z, a1.w)};
                     *(uint2*)(Y + (size_t)n * 64 + tf * 2) = o; }
        n = n0 + j0 + 2;
        if (n < N) { uint2 o = {pack2(a2.x, a2.y), pack2(a2.z, a2.w)};
                     *(uint2*)(Y + (size_t)n * 64 + tf * 2) = o; }
        n = n0 + j0 + 3;
        if (n < N) { uint2 o = {pack2(a3.x, a3.y), pack2(a3.z, a3.w)};
                     *(uint2*)(Y + (size_t)n * 64 + tf * 2) = o; }
    }
}

// ---------------- conv scatter (CSR, one wave per node, bf16 rows) + bias + relu ----------------
// T: [N*64] uint (bf16x2). Lane handles feats {lane*2, lane*2+1}. fp32 accumulate.
__global__ __launch_bounds__(256) void conv_kernel(const uint32_t* __restrict__ T,
                                                   const int* __restrict__ rp,
                                                   const int2* __restrict__ edges,
                                                   const float* __restrict__ dinv,
                                                   const float* __restrict__ bias,
                                                   uint32_t* __restrict__ OUT, int N) {
    int wid = (blockIdx.x * TB + threadIdx.x) >> 6;  // one wave per node
    int lane = threadIdx.x & 63;
    if (wid >= N) return;
    int d = wid;
    float dv = dinv[d];
    uint32_t td = T[(size_t)d * 64 + lane];
    float accx = dv * dv * blo(td);
    float accy = dv * dv * bhi(td);
    int e0 = rp[d], e1 = rp[d + 1];
#pragma unroll 4
    for (int e = e0; e < e1; ++e) {
        int2 pr = edges[e];
        float w = __int_as_float(pr.y);
        uint32_t tv = T[(size_t)pr.x * 64 + lane];
        accx = fmaf(w, blo(tv), accx);
        accy = fmaf(w, bhi(tv), accy);
    }
    float2 b = *(const float2*)(bias + lane * 2);
    OUT[(size_t)d * 64 + lane] = pack2(fmaxf(accx + b.x, 0.0f), fmaxf(accy + b.y, 0.0f));
}

// ---------------- mean pool (batch sorted; bf16 input, fp32 atomics) ----------------
#define NPB 256
__global__ __launch_bounds__(128) void pool_kernel(const uint16_t* __restrict__ Hh,
                                                   const int* __restrict__ batch, int N,
                                                   float* __restrict__ gsum, int* __restrict__ gcnt) {
    int f = threadIdx.x;  // 0..127
    int n0 = blockIdx.x * NPB;
    if (n0 >= N) return;
    int n1 = min(n0 + NPB, N);
    int cur = batch[n0];
    float acc = 0.0f;
    int c = 0;
    for (int n = n0; n < n1; ++n) {
        int b = batch[n];
        if (b != cur) {
            atomicAdd(&gsum[cur * 128 + f], acc);
            if (f == 0) atomicAdd(&gcnt[cur], c);
            acc = 0.0f; c = 0; cur = b;
        }
        acc += __uint_as_float(((uint32_t)Hh[(size_t)n * 128 + f]) << 16);
        c++;
    }
    atomicAdd(&gsum[cur * 128 + f], acc);
    if (f == 0) atomicAdd(&gcnt[cur], c);
}

// ---------------- head: mean, fc1+relu, fc2, log_softmax (fp32) ----------------
__global__ __launch_bounds__(128) void head_kernel(const float* __restrict__ gsum,
                                                   const int* __restrict__ gcnt,
                                                   const float* __restrict__ fcW1,
                                                   const float* __restrict__ fcb1,
                                                   const float* __restrict__ fcW2,
                                                   const float* __restrict__ fcb2,
                                                   float* __restrict__ out) {
    __shared__ float gx[128], hid[128], lg[10];
    int g = blockIdx.x, t = threadIdx.x;
    float cntf = fmaxf((float)gcnt[g], 1.0f);
    gx[t] = gsum[g * 128 + t] / cntf;
    __syncthreads();
    float a = fcb1[t];
    for (int k = 0; k < 128; ++k) a = fmaf(gx[k], fcW1[k * 128 + t], a);
    hid[t] = fmaxf(a, 0.0f);
    __syncthreads();
    if (t < 10) {
        float a2 = fcb2[t];
        for (int k = 0; k < 128; ++k) a2 = fmaf(hid[k], fcW2[k * 10 + t], a2);
        lg[t] = a2;
    }
    __syncthreads();
    if (t < 10) {
        float m = -1e30f;
        for (int j = 0; j < 10; ++j) m = fmaxf(m, lg[j]);
        float se = 0.0f;
        for (int j = 0; j < 10; ++j) se += expf(lg[j] - m);
        out[g * 10 + t] = lg[t] - m - logf(se);
    }
}

// ---------------- launch ----------------
extern "C" void kernel_launch(void* const* d_in, const int* in_sizes, int n_in,
                              void* d_out, int out_size, void* d_ws, size_t ws_size,
                              hipStream_t stream) {
    const float* x    = (const float*)d_in[0];
    const int*   ei   = (const int*)d_in[1];
    const int*   batch= (const int*)d_in[2];
    const float* W1   = (const float*)d_in[3];
    const float* b1   = (const float*)d_in[4];
    const float* W2   = (const float*)d_in[5];
    const float* b2   = (const float*)d_in[6];
    const float* fcW1 = (const float*)d_in[7];
    const float* fcb1 = (const float*)d_in[8];
    const float* fcW2 = (const float*)d_in[9];
    const float* fcb2 = (const float*)d_in[10];
    float* out = (float*)d_out;

    int N = in_sizes[0] / 128;
    int E = in_sizes[1] / 2;
    const int* src = ei;
    const int* dst = ei + E;

    // workspace carve-out (256B aligned)
    char* basep = (char*)d_ws;
    size_t off = 0;
    auto alloc = [&](size_t bytes) -> void* {
        off = (off + 255) & ~(size_t)255;
        void* p = basep + off;
        off += bytes;
        return p;
    };
    float*     dinv  = (float*)alloc((size_t)N * 4);
    int*       cnt   = (int*)alloc((size_t)N * 4);
    int*       rp    = (int*)alloc((size_t)(N + 1) * 4);
    int*       rfill = (int*)alloc((size_t)N * 4);
    int*       bsum  = (int*)alloc(1024 * 4);
    int2*      edges = (int2*)alloc((size_t)E * 8);
    uint32_t*  A     = (uint32_t*)alloc((size_t)N * 128 * 2);  // bf16 [N,128]
    uint32_t*  B     = (uint32_t*)alloc((size_t)N * 128 * 2);  // bf16 [N,128]
    float*     gsum  = (float*)alloc(64 * 128 * 4);
    int*       gcnt  = (int*)alloc(64 * 4);

    int nblk = (N + 1023) / 1024;
    int ntiles = (N + 31) / 32;

    // 1) degrees + dinv
    zero_u32<<<(N + TB - 1) / TB, TB, 0, stream>>>((uint32_t*)cnt, N);
    hist_kernel<<<(E + TB - 1) / TB, TB, 0, stream>>>(dst, E, cnt);
    dinv_kernel<<<(N + TB - 1) / TB, TB, 0, stream>>>(cnt, dinv, N);

    // 2) CSR build (counting sort by dst)
    scan1_kernel<<<nblk, 256, 0, stream>>>(cnt, N, rp, bsum);
    scan2_kernel<<<1, 256, 0, stream>>>(bsum, nblk);
    scan3_kernel<<<(N + TB - 1) / TB, TB, 0, stream>>>(rp, rfill, bsum, N, E);
    fill_kernel<<<(E + TB - 1) / TB, TB, 0, stream>>>(src, dst, E, rfill, edges, dinv);

    // 3) conv1: A = bf16(x@W1) ; B = bf16(relu(scatter(A) + b1))
    gemm128_kernel<false><<<1024, 256, 0, stream>>>(x, W1, A, N, ntiles);
    conv_kernel<<<(N + 3) / 4, TB, 0, stream>>>(A, rp, edges, dinv, b1, B, N);

    // 4) conv2: A = bf16(B@W2) ; B = bf16(relu(scatter(A) + b2))
    gemm128_kernel<true><<<1024, 256, 0, stream>>>(B, W2, A, N, ntiles);
    conv_kernel<<<(N + 3) / 4, TB, 0, stream>>>(A, rp, edges, dinv, b2, B, N);

    // 5) mean pool (reads bf16)
    zero_u32<<<(64 * 128 + TB - 1) / TB, TB, 0, stream>>>((uint32_t*)gsum, 64 * 128);
    zero_u32<<<1, 64, 0, stream>>>((uint32_t*)gcnt, 64);
    pool_kernel<<<(N + NPB - 1) / NPB, 128, 0, stream>>>((const uint16_t*)B, batch, N, gsum, gcnt);

    // 6) head
    head_kernel<<<64, 128, 0, stream>>>(gsum, gcnt, fcW1, fcb1, fcW2, fcb2, out);
}

// Round 15
// 537.248 us; speedup vs baseline: 1.3587x; 1.1691x over previous
//
#include <hip/hip_runtime.h>
#include <stdint.h>

#define TB 256

typedef short short8 __attribute__((ext_vector_type(8)));
typedef float f32x4 __attribute__((ext_vector_type(4)));

// ---------------- bf16 helpers (bit-level, RTNE) ----------------
__device__ __forceinline__ float blo(uint32_t v) { return __uint_as_float(v << 16); }
__device__ __forceinline__ float bhi(uint32_t v) { return __uint_as_float(v & 0xffff0000u); }
__device__ __forceinline__ uint32_t f2b(float f) {  // RTNE, returns low 16 bits
    uint32_t u = __float_as_uint(f);
    return (u + 0x7fffu + ((u >> 16) & 1u)) >> 16;
}
__device__ __forceinline__ uint32_t pack2(float lo, float hi) {
    return f2b(lo) | (f2b(hi) << 16);
}

// ---------------- utility ----------------
__global__ void zero_u32(uint32_t* __restrict__ p, int n) {
    int i = blockIdx.x * blockDim.x + threadIdx.x;
    if (i < n) p[i] = 0u;
}

// ---------------- degree histogram ----------------
__global__ void hist_kernel(const int* __restrict__ dst, int E, int* __restrict__ cnt) {
    int e = blockIdx.x * blockDim.x + threadIdx.x;
    if (e < E) atomicAdd(&cnt[dst[e]], 1);
}

__global__ void dinv_kernel(const int* __restrict__ cnt, float* __restrict__ dinv, int N) {
    int n = blockIdx.x * blockDim.x + threadIdx.x;
    if (n < N) dinv[n] = rsqrtf((float)cnt[n] + 1.0f);   // +1 for self-loop
}

// ---------------- exclusive scan over cnt -> row_ptr (3 phases) ----------------
__global__ __launch_bounds__(256) void scan1_kernel(const int* __restrict__ cnt, int N,
                                                    int* __restrict__ rp, int* __restrict__ bsum) {
    __shared__ int sh[256];
    int t = threadIdx.x;
    int base = blockIdx.x * 1024 + t * 4;
    int v0 = (base + 0 < N) ? cnt[base + 0] : 0;
    int v1 = (base + 1 < N) ? cnt[base + 1] : 0;
    int v2 = (base + 2 < N) ? cnt[base + 2] : 0;
    int v3 = (base + 3 < N) ? cnt[base + 3] : 0;
    int s = v0 + v1 + v2 + v3;
    sh[t] = s;
    __syncthreads();
    for (int off = 1; off < 256; off <<= 1) {
        int add = (t >= off) ? sh[t - off] : 0;
        __syncthreads();
        sh[t] += add;
        __syncthreads();
    }
    int incl = sh[t];
    if (t == 255) bsum[blockIdx.x] = incl;
    int run = incl - s;  // exclusive
    if (base + 0 < N) rp[base + 0] = run; run += v0;
    if (base + 1 < N) rp[base + 1] = run; run += v1;
    if (base + 2 < N) rp[base + 2] = run; run += v2;
    if (base + 3 < N) rp[base + 3] = run;
}

__global__ __launch_bounds__(256) void scan2_kernel(int* __restrict__ bsum, int nblk) {
    __shared__ int sh[256];
    int t = threadIdx.x;
    int v = (t < nblk) ? bsum[t] : 0;
    sh[t] = v;
    __syncthreads();
    for (int off = 1; off < 256; off <<= 1) {
        int add = (t >= off) ? sh[t - off] : 0;
        __syncthreads();
        sh[t] += add;
        __syncthreads();
    }
    if (t < nblk) bsum[t] = sh[t] - v;  // exclusive
}

__global__ void scan3_kernel(int* __restrict__ rp, int* __restrict__ rfill,
                             const int* __restrict__ bsum, int N, int E) {
    int i = blockIdx.x * blockDim.x + threadIdx.x;
    if (i < N) {
        int v = rp[i] + bsum[i >> 10];
        rp[i] = v;
        rfill[i] = v;
    }
    if (i == 0) rp[N] = E;
}

// ---------------- CSR fill: (src, weight) per dst ----------------
__global__ void fill_kernel(const int* __restrict__ src, const int* __restrict__ dst, int E,
                            int* __restrict__ rfill, int2* __restrict__ edges,
                            const float* __restrict__ dinv) {
    int e = blockIdx.x * blockDim.x + threadIdx.x;
    if (e < E) {
        int s = src[e], d = dst[e];
        int pos = atomicAdd(&rfill[d], 1);
        int2 pr;
        pr.x = s;
        pr.y = __float_as_int(dinv[s] * dinv[d]);
        edges[pos] = pr;
    }
}

// ---------------- MFMA GEMM: Y[N,128](bf16) = X[N,128] @ W[128,128](f32) ----------------
// v_mfma_f32_16x16x32_bf16. W staged bf16-transposed in LDS [c][k], row stride 272B.
// Block = 256 thr = 4 waves; block tile = 32 rows x 128 cols.
// Wave w: rows +16*(w&1), cols 64*(w>>1). Per wave: 4 col-tiles x 4 K-steps = 16 MFMA.
// Frag layouts (m89/m91-verified family): A: row=l&15, k=(l>>4)*8+j ; B: col=l&15, same k.
// C/D: col=l&15, row=(l>>4)*4+i.
template <bool BF16IN>
__global__ __launch_bounds__(256) void gemm_mfma_kernel(const void* __restrict__ Xv,
                                                        const float* __restrict__ W,
                                                        uint16_t* __restrict__ Y,  // [N*128] bf16
                                                        int N, int ntiles) {
    __shared__ uint16_t Wb[128][136];  // [col][k], stride 272B (16B-aligned, anti-conflict pad)

    // stage W (fp32 row-major [k][c]) -> bf16 transposed LDS [c][k]
    for (int idx = threadIdx.x; idx < 128 * 32; idx += 256) {
        int k = idx >> 5;           // 0..127
        int c4 = (idx & 31) * 4;    // 0..124
        float4 wv = *(const float4*)(W + (size_t)k * 128 + c4);
        Wb[c4 + 0][k] = (uint16_t)f2b(wv.x);
        Wb[c4 + 1][k] = (uint16_t)f2b(wv.y);
        Wb[c4 + 2][k] = (uint16_t)f2b(wv.z);
        Wb[c4 + 3][k] = (uint16_t)f2b(wv.w);
    }
    __syncthreads();

    int w = threadIdx.x >> 6;       // wave 0..3
    int l = threadIdx.x & 63;       // lane
    int rowOff = (w & 1) * 16;      // 0 / 16
    int colBase = (w >> 1) * 64;    // 0 / 64
    int lr = l & 15;                // frag row/col index
    int k8 = (l >> 4) * 8;          // frag k-offset

    // B fragments: tile-invariant, hoist to registers (4 ct x 4 kk)
    short8 bfrag[4][4];
#pragma unroll
    for (int ct = 0; ct < 4; ++ct)
#pragma unroll
        for (int kk = 0; kk < 4; ++kk)
            bfrag[ct][kk] = *(const short8*)&Wb[colBase + ct * 16 + lr][kk * 32 + k8];

    for (int tile = blockIdx.x; tile < ntiles; tile += gridDim.x) {
        int rbase = tile * 32 + rowOff;
        int r = min(rbase + lr, N - 1);  // A-frag source row (clamped)

        short8 afrag[4];
        if (BF16IN) {
            const uint16_t* xr = (const uint16_t*)Xv + (size_t)r * 128 + k8;
#pragma unroll
            for (int kk = 0; kk < 4; ++kk)
                afrag[kk] = *(const short8*)(xr + kk * 32);
        } else {
            const float* xr = (const float*)Xv + (size_t)r * 128 + k8;
#pragma unroll
            for (int kk = 0; kk < 4; ++kk) {
                float4 f0 = *(const float4*)(xr + kk * 32);
                float4 f1 = *(const float4*)(xr + kk * 32 + 4);
                short8 a;
                a[0] = (short)f2b(f0.x); a[1] = (short)f2b(f0.y);
                a[2] = (short)f2b(f0.z); a[3] = (short)f2b(f0.w);
                a[4] = (short)f2b(f1.x); a[5] = (short)f2b(f1.y);
                a[6] = (short)f2b(f1.z); a[7] = (short)f2b(f1.w);
                afrag[kk] = a;
            }
        }

        f32x4 acc[4] = {{0, 0, 0, 0}, {0, 0, 0, 0}, {0, 0, 0, 0}, {0, 0, 0, 0}};
#pragma unroll
        for (int kk = 0; kk < 4; ++kk)
#pragma unroll
            for (int ct = 0; ct < 4; ++ct)
                acc[ct] = __builtin_amdgcn_mfma_f32_16x16x32_bf16(afrag[kk], bfrag[ct][kk],
                                                                  acc[ct], 0, 0, 0);

        // store: row = rbase + (l>>4)*4 + i, col = colBase + ct*16 + (l&15)
        int rs = rbase + (l >> 4) * 4;
#pragma unroll
        for (int i = 0; i < 4; ++i) {
            int rr = rs + i;
            if (rr < N) {
                uint16_t* yr = Y + (size_t)rr * 128 + colBase + lr;
#pragma unroll
                for (int ct = 0; ct < 4; ++ct)
                    yr[ct * 16] = (uint16_t)f2b(acc[ct][i]);
            }
        }
    }
}

// ---------------- conv scatter (CSR, one wave per node, bf16 rows) + bias + relu ----------------
// T: [N*64] uint (bf16x2). Lane handles feats {lane*2, lane*2+1}. fp32 accumulate.
__global__ __launch_bounds__(256) void conv_kernel(const uint32_t* __restrict__ T,
                                                   const int* __restrict__ rp,
                                                   const int2* __restrict__ edges,
                                                   const float* __restrict__ dinv,
                                                   const float* __restrict__ bias,
                                                   uint32_t* __restrict__ OUT, int N) {
    int wid = (blockIdx.x * TB + threadIdx.x) >> 6;  // one wave per node
    int lane = threadIdx.x & 63;
    if (wid >= N) return;
    int d = wid;
    float dv = dinv[d];
    uint32_t td = T[(size_t)d * 64 + lane];
    float accx = dv * dv * blo(td);
    float accy = dv * dv * bhi(td);
    int e0 = rp[d], e1 = rp[d + 1];
#pragma unroll 4
    for (int e = e0; e < e1; ++e) {
        int2 pr = edges[e];
        float w = __int_as_float(pr.y);
        uint32_t tv = T[(size_t)pr.x * 64 + lane];
        accx = fmaf(w, blo(tv), accx);
        accy = fmaf(w, bhi(tv), accy);
    }
    float2 b = *(const float2*)(bias + lane * 2);
    OUT[(size_t)d * 64 + lane] = pack2(fmaxf(accx + b.x, 0.0f), fmaxf(accy + b.y, 0.0f));
}

// ---------------- mean pool (batch sorted; bf16 input, fp32 atomics) ----------------
#define NPB 256
__global__ __launch_bounds__(128) void pool_kernel(const uint16_t* __restrict__ Hh,
                                                   const int* __restrict__ batch, int N,
                                                   float* __restrict__ gsum, int* __restrict__ gcnt) {
    int f = threadIdx.x;  // 0..127
    int n0 = blockIdx.x * NPB;
    if (n0 >= N) return;
    int n1 = min(n0 + NPB, N);
    int cur = batch[n0];
    float acc = 0.0f;
    int c = 0;
    for (int n = n0; n < n1; ++n) {
        int b = batch[n];
        if (b != cur) {
            atomicAdd(&gsum[cur * 128 + f], acc);
            if (f == 0) atomicAdd(&gcnt[cur], c);
            acc = 0.0f; c = 0; cur = b;
        }
        acc += __uint_as_float(((uint32_t)Hh[(size_t)n * 128 + f]) << 16);
        c++;
    }
    atomicAdd(&gsum[cur * 128 + f], acc);
    if (f == 0) atomicAdd(&gcnt[cur], c);
}

// ---------------- head: mean, fc1+relu, fc2, log_softmax (fp32) ----------------
__global__ __launch_bounds__(128) void head_kernel(const float* __restrict__ gsum,
                                                   const int* __restrict__ gcnt,
                                                   const float* __restrict__ fcW1,
                                                   const float* __restrict__ fcb1,
                                                   const float* __restrict__ fcW2,
                                                   const float* __restrict__ fcb2,
                                                   float* __restrict__ out) {
    __shared__ float gx[128], hid[128], lg[10];
    int g = blockIdx.x, t = threadIdx.x;
    float cntf = fmaxf((float)gcnt[g], 1.0f);
    gx[t] = gsum[g * 128 + t] / cntf;
    __syncthreads();
    float a = fcb1[t];
    for (int k = 0; k < 128; ++k) a = fmaf(gx[k], fcW1[k * 128 + t], a);
    hid[t] = fmaxf(a, 0.0f);
    __syncthreads();
    if (t < 10) {
        float a2 = fcb2[t];
        for (int k = 0; k < 128; ++k) a2 = fmaf(hid[k], fcW2[k * 10 + t], a2);
        lg[t] = a2;
    }
    __syncthreads();
    if (t < 10) {
        float m = -1e30f;
        for (int j = 0; j < 10; ++j) m = fmaxf(m, lg[j]);
        float se = 0.0f;
        for (int j = 0; j < 10; ++j) se += expf(lg[j] - m);
        out[g * 10 + t] = lg[t] - m - logf(se);
    }
}

// ---------------- launch ----------------
extern "C" void kernel_launch(void* const* d_in, const int* in_sizes, int n_in,
                              void* d_out, int out_size, void* d_ws, size_t ws_size,
                              hipStream_t stream) {
    const float* x    = (const float*)d_in[0];
    const int*   ei   = (const int*)d_in[1];
    const int*   batch= (const int*)d_in[2];
    const float* W1   = (const float*)d_in[3];
    const float* b1   = (const float*)d_in[4];
    const float* W2   = (const float*)d_in[5];
    const float* b2   = (const float*)d_in[6];
    const float* fcW1 = (const float*)d_in[7];
    const float* fcb1 = (const float*)d_in[8];
    const float* fcW2 = (const float*)d_in[9];
    const float* fcb2 = (const float*)d_in[10];
    float* out = (float*)d_out;

    int N = in_sizes[0] / 128;
    int E = in_sizes[1] / 2;
    const int* src = ei;
    const int* dst = ei + E;

    // workspace carve-out (256B aligned)
    char* basep = (char*)d_ws;
    size_t off = 0;
    auto alloc = [&](size_t bytes) -> void* {
        off = (off + 255) & ~(size_t)255;
        void* p = basep + off;
        off += bytes;
        return p;
    };
    float*     dinv  = (float*)alloc((size_t)N * 4);
    int*       cnt   = (int*)alloc((size_t)N * 4);
    int*       rp    = (int*)alloc((size_t)(N + 1) * 4);
    int*       rfill = (int*)alloc((size_t)N * 4);
    int*       bsum  = (int*)alloc(1024 * 4);
    int2*      edges = (int2*)alloc((size_t)E * 8);
    uint32_t*  A     = (uint32_t*)alloc((size_t)N * 128 * 2);  // bf16 [N,128]
    uint32_t*  B     = (uint32_t*)alloc((size_t)N * 128 * 2);  // bf16 [N,128]
    float*     gsum  = (float*)alloc(64 * 128 * 4);
    int*       gcnt  = (int*)alloc(64 * 4);

    int nblk = (N + 1023) / 1024;
    int ntiles = (N + 31) / 32;

    // 1) degrees + dinv
    zero_u32<<<(N + TB - 1) / TB, TB, 0, stream>>>((uint32_t*)cnt, N);
    hist_kernel<<<(E + TB - 1) / TB, TB, 0, stream>>>(dst, E, cnt);
    dinv_kernel<<<(N + TB - 1) / TB, TB, 0, stream>>>(cnt, dinv, N);

    // 2) CSR build (counting sort by dst)
    scan1_kernel<<<nblk, 256, 0, stream>>>(cnt, N, rp, bsum);
    scan2_kernel<<<1, 256, 0, stream>>>(bsum, nblk);
    scan3_kernel<<<(N + TB - 1) / TB, TB, 0, stream>>>(rp, rfill, bsum, N, E);
    fill_kernel<<<(E + TB - 1) / TB, TB, 0, stream>>>(src, dst, E, rfill, edges, dinv);

    // 3) conv1: A = bf16(x@W1) ; B = bf16(relu(scatter(A) + b1))
    gemm_mfma_kernel<false><<<1024, 256, 0, stream>>>(x, W1, (uint16_t*)A, N, ntiles);
    conv_kernel<<<(N + 3) / 4, TB, 0, stream>>>(A, rp, edges, dinv, b1, B, N);

    // 4) conv2: A = bf16(B@W2) ; B = bf16(relu(scatter(A) + b2))
    gemm_mfma_kernel<true><<<1024, 256, 0, stream>>>(B, W2, (uint16_t*)A, N, ntiles);
    conv_kernel<<<(N + 3) / 4, TB, 0, stream>>>(A, rp, edges, dinv, b2, B, N);

    // 5) mean pool (reads bf16)
    zero_u32<<<(64 * 128 + TB - 1) / TB, TB, 0, stream>>>((uint32_t*)gsum, 64 * 128);
    zero_u32<<<1, 64, 0, stream>>>((uint32_t*)gcnt, 64);
    pool_kernel<<<(N + NPB - 1) / NPB, 128, 0, stream>>>((const uint16_t*)B, batch, N, gsum, gcnt);

    // 6) head
    head_kernel<<<64, 128, 0, stream>>>(gsum, gcnt, fcW1, fcb1, fcW2, fcb2, out);
}